// Round 8
// baseline (1258.530 us; speedup 1.0000x reference)
//
#include <hip/hip_runtime.h>

// H=W=1024, T=16, 20 iterations. Intermediates in two zero-bordered padded
// buffers: PH x PITCH floats, pixel (h,w) at [(h+1)*PITCH + (w+1)]. Border
// (col 0, cols >=1025, row 0, rows >=1025) is zero.
//
// R8 = R7 structure with the NaN fix:
//  - single cooperative LDS staging phase (2 barriers/block total);
//  - staged slabs: every LDS cell reachable by a clamped sample is WRITTEN
//    (bbox data, zero pad column when pitch>bw, 144-float zero tail after the
//    last slab) -> weight-0 corner reads hit finite values, never 0*NaN;
//  - global-fallback path uses R5's masked idx/weight (no OOB reads).
constexpr int W = 1024;
constexpr int H = 1024;
constexpr int T = 16;
constexpr int ITERS = 20;
constexpr int PITCH = 1040;           // floats per padded row
constexpr int PH = H + 2;             // 1026 rows
constexpr int PAD_ELEMS = PH * PITCH;
constexpr int TILES_X = W / 16;       // 64
constexpr int TILES_Y = H / 16;       // 64
constexpr int BUDGET = 9000;          // LDS stage pool (floats)

typedef float f2 __attribute__((ext_vector_type(2), aligned(4)));

// coef per transform t: {p, Ax, Bx, Cxp, Ay, By, Cyp, 0}; Cxp/Cyp include the
// +1 pad shift, so ixp = Ax*w + Bx*h + Cxp is the PADDED x coordinate.
__global__ void setup_coef(const float* __restrict__ theta,
                           const float* __restrict__ probs,
                           float* __restrict__ coef) {
    int t = threadIdx.x;
    if (t >= T) return;
    float sum = 0.f;
    for (int i = 0; i < T; ++i) sum += probs[i];
    float p = probs[t] / sum;
    const float* th = theta + 6 * t;
    float a = th[0], b = th[1], c = th[2];
    float d = th[3], e = th[4], f = th[5];
    float Cx = a * ((1.0f - (float)W) * 0.5f)
             + b * ((1.0f - (float)H) * 0.5f)
             + (c + 1.0f) * ((float)W * 0.5f) - 0.5f;
    float Cy = d * ((1.0f - (float)W) * 0.5f)
             + e * ((1.0f - (float)H) * 0.5f)
             + (f + 1.0f) * ((float)H * 0.5f) - 0.5f;
    float* o = coef + 8 * t;
    o[0] = p;  o[1] = a;  o[2] = b;  o[3] = Cx + 1.0f;
    o[4] = d;  o[5] = e;  o[6] = Cy + 1.0f; o[7] = 0.f;
}

__global__ __launch_bounds__(256) void copy_in(const float* __restrict__ src,
                                               float* __restrict__ dst) {
    int i = blockIdx.x * 256 + threadIdx.x;   // i in [0, H*W)
    int h = i >> 10, w = i & 1023;
    dst[(h + 1) * PITCH + (w + 1)] = src[i];
}

// meta layout per staged transform (16 floats, float4-readable):
//  [0..3]  p, Ax, Bx, Cx
//  [4..7]  Ay, By, Cy, xlo
//  [8..11] ylo, xhi, yhi, pitchf
//  [12..15] slabBase, bwf, bhf, gbasef
__global__ __launch_bounds__(256) void ifs_iter(const float* __restrict__ in,
                                                float* __restrict__ out,
                                                const float* __restrict__ coef,
                                                const float* __restrict__ base,
                                                int dstPitch, int dstOff,
                                                int add_base) {
    __shared__ __align__(16) float sbuf[BUDGET + 144];
    __shared__ __align__(16) float mL[T][16];
    __shared__ __align__(16) float mG[T][8];
    __shared__ int flagL[T];
    __shared__ int cnt[2];
    __shared__ int totRun;

    int lid  = threadIdx.x;
    int lane = lid & 63;
    int wv   = lid >> 6;

    // ---- phase 1: classification (wave 0 only; in-wave LDS ordering) ----
    if (wv == 0) {
        if (lane == 0) { cnt[0] = 0; cnt[1] = 0; }
        if (lane < T) {
            const float* c = coef + lane * 8;
            float p = c[0], Ax = c[1], Bx = c[2], Cx = c[3];
            float Ay = c[4], By = c[5], Cy = c[6];
            float w0 = (float)(blockIdx.x * 16), w1 = w0 + 15.f;
            float h0 = (float)(blockIdx.y * 16), h1 = h0 + 15.f;
            float ixmin = Cx + (Ax >= 0.f ? Ax * w0 : Ax * w1) + (Bx >= 0.f ? Bx * h0 : Bx * h1);
            float ixmax = Cx + (Ax >= 0.f ? Ax * w1 : Ax * w0) + (Bx >= 0.f ? Bx * h1 : Bx * h0);
            float iymin = Cy + (Ay >= 0.f ? Ay * w0 : Ay * w1) + (By >= 0.f ? By * h0 : By * h1);
            float iymax = Cy + (Ay >= 0.f ? Ay * w1 : Ay * w0) + (By >= 0.f ? By * h1 : By * h0);
            bool hit = (ixmax > 0.f) & (ixmin < 1025.f) & (iymax > 0.f) & (iymin < 1025.f);
            if (hit) {
                float xlo = fmaxf(floorf(ixmin) - 1.f, 0.f);
                float xhi = fminf(floorf(ixmax) + 2.f, 1025.f);
                float ylo = fmaxf(floorf(iymin) - 1.f, 0.f);
                float yhi = fminf(floorf(iymax) + 2.f, 1025.f);
                int bwI = (int)(xhi - xlo) + 1;
                int bhI = (int)(yhi - ylo) + 1;
                if (bwI <= 64 && bhI <= 64) {
                    int s = atomicAdd(&cnt[0], 1);
                    int pitchI = bwI | 1;            // odd pitch
                    float4* q = (float4*)mL[s];
                    q[0] = make_float4(p, Ax, Bx, Cx);
                    q[1] = make_float4(Ay, By, Cy, xlo);
                    q[2] = make_float4(ylo, xhi, yhi, (float)pitchI);
                    q[3] = make_float4(0.f, (float)bwI, (float)bhI,
                                       fmaf(ylo, (float)PITCH, xlo));
                } else {
                    int s = atomicAdd(&cnt[1], 1);
                    float4* q = (float4*)mG[s];
                    q[0] = make_float4(p, Ax, Bx, Cx);
                    q[1] = make_float4(Ay, By, Cy, 0.f);
                }
            }
        }
        // ---- phase 2: slab offsets (lane 0; sees lane 0..15 writes) ----
        if (lane == 0) {
            int n0 = cnt[0];
            int run = 0;
            for (int i = 0; i < n0; ++i) {
                int pitchI = (int)mL[i][11];
                int slab   = (int)mL[i][14] * pitchI;
                if (run + slab <= BUDGET) {
                    mL[i][12] = (float)run;
                    flagL[i] = 1;
                    run += slab;
                } else {                    // overflow -> global path
                    flagL[i] = 0;
                    int s = cnt[1]++;
                    float4* q = (float4*)mG[s];
                    const float4* m = (const float4*)mL[i];
                    q[0] = m[0];
                    q[1] = m[1];
                }
            }
            totRun = run;
        }
    }
    __syncthreads();
    int nL = cnt[0], nG = cnt[1];
    int tr = totRun;

    // ---- phase 3: cooperative staging (all 256 threads, coalesced) ----
    for (int i = 0; i < nL; ++i) {
        if (!flagL[i]) continue;
        int pitchI = (int)mL[i][11];
        int sb     = (int)mL[i][12];
        int bw     = (int)mL[i][13];
        int bh     = (int)mL[i][14];
        int gb     = (int)mL[i][15];
        int colbits = bw <= 16 ? 4 : (bw <= 32 ? 5 : 6);
        int rpp = 256 >> colbits;             // rows per pass
        int c  = lid & ((1 << colbits) - 1);
        int r0 = lid >> colbits;
        for (int r = r0; r < bh; r += rpp)
            if (c < bw) sbuf[sb + r * pitchI + c] = in[gb + r * PITCH + c];
        // pad column (pitch > bw) must be finite: clamped weight-0 reads hit it
        if (pitchI > bw && lid < bh) sbuf[sb + lid * pitchI + bw] = 0.f;
    }
    // zero tail after last slab: clamped row-bh reads of the last slab land here
    for (int j = lid; j < 144; j += 256) sbuf[tr + j] = 0.f;
    __syncthreads();

    // 8x8-per-wave mapping; 4 waves tile a 16x16 pixel block.
    int w = blockIdx.x * 16 + ((wv & 1) << 3) + (lane & 7);
    int h = blockIdx.y * 16 + ((wv >> 1) << 3) + (lane >> 3);
    float wf = (float)w, hf = (float)h;

    float acc = 0.f;

    // ---- phase 4: sample staged transforms from LDS (no barriers) ----
    for (int i = 0; i < nL; ++i) {
        if (!flagL[i]) continue;
        const float4* m = (const float4*)mL[i];
        float4 q0 = m[0], q1 = m[1], q2 = m[2], q3 = m[3];
        float p = q0.x, Ax = q0.y, Bx = q0.z, Cx = q0.w;
        float Ay = q1.x, By = q1.y, Cy = q1.z, xlo = q1.w;
        float ylo = q2.x, xhi = q2.y, yhi = q2.z, pitchf = q2.w;
        float basef = q3.x;
        int pitchI = (int)pitchf;

        float x = fmaf(Ax, wf, fmaf(Bx, hf, Cx));
        float y = fmaf(Ay, wf, fmaf(By, hf, Cy));
        x = fminf(fmaxf(x, xlo), xhi);       // clamp -> zero-border => exact 0
        y = fminf(fmaxf(y, ylo), yhi);
        float xf = floorf(x), yf = floorf(y);
        float fx = x - xf, fy = y - yf;
        int lidx = (int)fmaf(yf - ylo, pitchf, basef + (xf - xlo));
        float v00 = sbuf[lidx], v01 = sbuf[lidx + 1];
        float v10 = sbuf[lidx + pitchI], v11 = sbuf[lidx + pitchI + 1];
        float top = fmaf(fx, v01 - v00, v00);
        float bot = fmaf(fx, v11 - v10, v10);
        acc = fmaf(p, fmaf(fy, bot - top, top), acc);
    }

    // ---- phase 5: global-gather fallback (wide bbox / LDS overflow),
    //      masked form (R5): no OOB reads, pe=0 kills inactive lanes ----
    for (int i = 0; i < nG; ++i) {
        const float4* m = (const float4*)mG[i];
        float4 q0 = m[0], q1 = m[1];
        float p = q0.x, Ax = q0.y, Bx = q0.z, Cx = q0.w;
        float Ay = q1.x, By = q1.y, Cy = q1.z;
        float x = fmaf(Ax, wf, fmaf(Bx, hf, Cx));
        float y = fmaf(Ay, wf, fmaf(By, hf, Cy));
        float xf = floorf(x), yf = floorf(y);
        bool act = (xf >= 0.f) & (xf <= (float)W) & (yf >= 0.f) & (yf <= (float)H);
        int idx  = act ? (int)fmaf(yf, (float)PITCH, xf) : 0;   // exact (<2^24)
        float pe = act ? p : 0.f;
        f2 r0 = *(const f2*)(in + idx);
        f2 r1 = *(const f2*)(in + idx + PITCH);
        float fx = x - xf, fy = y - yf;
        float top = fmaf(fx, r0.y - r0.x, r0.x);
        float bot = fmaf(fx, r1.y - r1.x, r1.x);
        acc = fmaf(pe, fmaf(fy, bot - top, top), acc);
    }

    if (add_base) acc += base[0];
    out[h * dstPitch + w + dstOff] = acc;
}

extern "C" void kernel_launch(void* const* d_in, const int* in_sizes, int n_in,
                              void* d_out, int out_size, void* d_ws, size_t ws_size,
                              hipStream_t stream) {
    const float* canvas0 = (const float*)d_in[0];
    const float* theta   = (const float*)d_in[1];
    const float* probs   = (const float*)d_in[2];
    const float* base    = (const float*)d_in[3];
    float* out = (float*)d_out;

    float* bufA = (float*)d_ws;
    float* bufB = bufA + PAD_ELEMS;
    float* coef = bufB + PAD_ELEMS;

    // zero both padded buffers (borders must be 0; also kills 0xAA poison)
    hipMemsetAsync(d_ws, 0, (size_t)2 * PAD_ELEMS * sizeof(float), stream);

    setup_coef<<<1, 64, 0, stream>>>(theta, probs, coef);
    copy_in<<<(H * W) / 256, 256, 0, stream>>>(canvas0, bufA);

    dim3 block(256);
    dim3 grid(TILES_X, TILES_Y);

    const float* cur = bufA;
    for (int i = 0; i < ITERS; ++i) {
        bool last = (i == ITERS - 1);
        float* dst = last ? out : ((i & 1) ? bufA : bufB);
        int dstPitch = last ? W : PITCH;
        int dstOff   = last ? 0 : (PITCH + 1);
        ifs_iter<<<grid, block, 0, stream>>>(cur, dst, coef, base,
                                             dstPitch, dstOff, last ? 1 : 0);
        cur = dst;
    }
}

// Round 9
// 457.682 us; speedup vs baseline: 2.7498x; 2.7498x over previous
//
#include <hip/hip_runtime.h>

// H=W=1024, T=16, 20 iterations. Intermediates in two zero-bordered padded
// buffers: PH x PITCH floats, pixel (h,w) at [(h+1)*PITCH + (w+1)]. Zero
// borders => all 4 bilinear corners of any in-range sample are loadable
// unconditionally (zeros padding is exact).
//
// R9 = R5's proven scattered-gather quad body (LDS staging abandoned: R8
// showed it 3x worse) + SUPPORT-MASK PRUNING:
//  - each iteration writes a per-16x16-tile nonzero mask (__syncthreads_or);
//  - classification (inline, wave 0, ballot compaction - no atomics) skips
//    transforms whose source bbox intersects only zero tiles. A sample whose
//    corners all read exactly-zero data contributes exactly 0 -> exact skip.
//  - zero set grows as the IFS contracts (output absmax ~2e-9 vs input ~1),
//    so later iterations get cheaper.
constexpr int W = 1024;
constexpr int H = 1024;
constexpr int T = 16;
constexpr int ITERS = 20;
constexpr int PITCH = 1040;           // floats per padded row
constexpr int PH = H + 2;             // 1026 rows
constexpr int PAD_ELEMS = PH * PITCH;
constexpr int TILES_X = W / 16;       // 64
constexpr int TILES_Y = H / 16;       // 64
constexpr int NTILES = TILES_X * TILES_Y;

typedef float f2 __attribute__((ext_vector_type(2), aligned(4)));

// coef per transform t: {p, Ax, Bx, Cxp, Ay, By, Cyp, 0}; Cxp/Cyp include the
// +1 pad shift, so ixp = Ax*w + Bx*h + Cxp is the PADDED x coordinate.
__global__ void setup_coef(const float* __restrict__ theta,
                           const float* __restrict__ probs,
                           float* __restrict__ coef) {
    int t = threadIdx.x;
    if (t >= T) return;
    float sum = 0.f;
    for (int i = 0; i < T; ++i) sum += probs[i];
    float p = probs[t] / sum;
    const float* th = theta + 6 * t;
    float a = th[0], b = th[1], c = th[2];
    float d = th[3], e = th[4], f = th[5];
    float Cx = a * ((1.0f - (float)W) * 0.5f)
             + b * ((1.0f - (float)H) * 0.5f)
             + (c + 1.0f) * ((float)W * 0.5f) - 0.5f;
    float Cy = d * ((1.0f - (float)W) * 0.5f)
             + e * ((1.0f - (float)H) * 0.5f)
             + (f + 1.0f) * ((float)H * 0.5f) - 0.5f;
    float* o = coef + 8 * t;
    o[0] = p;  o[1] = a;  o[2] = b;  o[3] = Cx + 1.0f;
    o[4] = d;  o[5] = e;  o[6] = Cy + 1.0f; o[7] = 0.f;
}

__global__ __launch_bounds__(256) void copy_in(const float* __restrict__ src,
                                               float* __restrict__ dst) {
    int i = blockIdx.x * 256 + threadIdx.x;   // i in [0, H*W)
    int h = i >> 10, w = i & 1023;
    dst[(h + 1) * PITCH + (w + 1)] = src[i];
}

__global__ __launch_bounds__(256) void ifs_iter(const float* __restrict__ in,
                                                float* __restrict__ out,
                                                const float* __restrict__ coef,
                                                const int* __restrict__ maskIn,
                                                int* __restrict__ maskOut,
                                                const float* __restrict__ base,
                                                int dstPitch, int dstOff,
                                                int add_base) {
    // compacted active coefs: up to 16 + 3 zero-pad dummy transforms
    __shared__ float sc[(T + 3) * 8];
    __shared__ int sn;

    int lid  = threadIdx.x;
    int lane = lid & 63;
    int wv   = lid >> 6;

    // ---- classification: wave 0, lanes 0..15; ballot compaction ----
    if (wv == 0) {
        bool act = false;
        float cc[8] = {0, 0, 0, 0, 0, 0, 0, 0};
        if (lane < T) {
            const float* c = coef + lane * 8;
#pragma unroll
            for (int j = 0; j < 8; ++j) cc[j] = c[j];
            float Ax = cc[1], Bx = cc[2], Cx = cc[3];
            float Ay = cc[4], By = cc[5], Cy = cc[6];
            float w0 = (float)(blockIdx.x * 16), w1 = w0 + 15.f;
            float h0 = (float)(blockIdx.y * 16), h1 = h0 + 15.f;
            float ixmin = Cx + (Ax >= 0.f ? Ax * w0 : Ax * w1) + (Bx >= 0.f ? Bx * h0 : Bx * h1);
            float ixmax = Cx + (Ax >= 0.f ? Ax * w1 : Ax * w0) + (Bx >= 0.f ? Bx * h1 : Bx * h0);
            float iymin = Cy + (Ay >= 0.f ? Ay * w0 : Ay * w1) + (By >= 0.f ? By * h0 : By * h1);
            float iymax = Cy + (Ay >= 0.f ? Ay * w1 : Ay * w0) + (By >= 0.f ? By * h1 : By * h0);
            bool hit = (ixmax > 0.f) & (ixmin < 1025.f) & (iymax > 0.f) & (iymin < 1025.f);
            if (hit) {
                // conservative corner-pixel bbox (padded coords, +1 margin)
                float xlo = fmaxf(floorf(ixmin) - 1.f, 0.f);
                float xhi = fminf(floorf(ixmax) + 2.f, 1025.f);
                float ylo = fmaxf(floorf(iymin) - 1.f, 0.f);
                float yhi = fminf(floorf(iymax) + 2.f, 1025.f);
                // unpadded data range touched by corners
                int ux0 = max((int)xlo - 1, 0), ux1 = min((int)xhi - 1, 1023);
                int uy0 = max((int)ylo - 1, 0), uy1 = min((int)yhi - 1, 1023);
                int tx0 = ux0 >> 4, tx1 = ux1 >> 4;
                int ty0 = uy0 >> 4, ty1 = uy1 >> 4;
                int nt = (tx1 - tx0 + 1) * (ty1 - ty0 + 1);
                if (nt > 64) {
                    act = true;            // too big to scan: assume live
                } else {
                    for (int ty = ty0; ty <= ty1 && !act; ++ty)
                        for (int tx = tx0; tx <= tx1; ++tx)
                            if (maskIn[ty * TILES_X + tx]) { act = true; break; }
                }
            }
        }
        unsigned long long bal = __ballot(act);
        int nact = __popcll(bal);
        if (act) {
            int pos = __popcll(bal & ((1ull << lane) - 1ull));
#pragma unroll
            for (int j = 0; j < 8; ++j) sc[pos * 8 + j] = cc[j];
        }
        if (lane >= 40) sc[nact * 8 + (lane - 40)] = 0.f;  // 24 dummy floats
        if (lane == 0) sn = nact;
    }
    __syncthreads();
    int nact = sn;

    // 8x8-per-wave mapping; 4 waves tile a 16x16 pixel block.
    int w = blockIdx.x * 16 + ((wv & 1) << 3) + (lane & 7);
    int h = blockIdx.y * 16 + ((wv >> 1) << 3) + (lane >> 3);
    float wf = (float)w, hf = (float)h;

    float acc = 0.f;

    for (int g = 0; g < nact; g += 4) {   // wave-uniform trip count
        const float* c = sc + g * 8;
        float fx[4], fy[4], pe[4];
        int id0[4];
#pragma unroll
        for (int k = 0; k < 4; ++k) {
            const float* ck = c + k * 8;
            float p = ck[0], Ax = ck[1], Bx = ck[2], Cx = ck[3];
            float Ay = ck[4], By = ck[5], Cy = ck[6];
            float x = fmaf(Ax, wf, fmaf(Bx, hf, Cx));
            float y = fmaf(Ay, wf, fmaf(By, hf, Cy));
            float xf = floorf(x), yf = floorf(y);
            bool act = (xf >= 0.f) & (xf <= (float)W) & (yf >= 0.f) & (yf <= (float)H);
            id0[k] = act ? (int)fmaf(yf, (float)PITCH, xf) : 0;  // exact (<2^24)
            pe[k]  = act ? p : 0.f;
            fx[k] = x - xf;
            fy[k] = y - yf;
        }
        // 8 independent 8B gathers in flight (corner pairs are x-adjacent)
        f2 r0[4], r1[4];
#pragma unroll
        for (int k = 0; k < 4; ++k) {
            r0[k] = *(const f2*)(in + id0[k]);
            r1[k] = *(const f2*)(in + id0[k] + PITCH);
        }
#pragma unroll
        for (int k = 0; k < 4; ++k) {
            float top = fmaf(fx[k], r0[k].y - r0[k].x, r0[k].x);
            float bot = fmaf(fx[k], r1[k].y - r1[k].x, r1[k].x);
            acc = fmaf(pe[k], fmaf(fy[k], bot - top, top), acc);
        }
    }

    // ---- support mask for the next iteration (pre-base value) ----
    int any = __syncthreads_or(acc != 0.f ? 1 : 0);
    if (lid == 0) maskOut[blockIdx.y * TILES_X + blockIdx.x] = any;

    if (add_base) acc += base[0];
    out[h * dstPitch + w + dstOff] = acc;
}

extern "C" void kernel_launch(void* const* d_in, const int* in_sizes, int n_in,
                              void* d_out, int out_size, void* d_ws, size_t ws_size,
                              hipStream_t stream) {
    const float* canvas0 = (const float*)d_in[0];
    const float* theta   = (const float*)d_in[1];
    const float* probs   = (const float*)d_in[2];
    const float* base    = (const float*)d_in[3];
    float* out = (float*)d_out;

    float* bufA = (float*)d_ws;
    float* bufB = bufA + PAD_ELEMS;
    float* coef = bufB + PAD_ELEMS;
    int* maskP0 = (int*)(coef + T * 8);
    int* maskP1 = maskP0 + NTILES;

    // zero both padded buffers (borders must be 0; also kills 0xAA poison)
    hipMemsetAsync(d_ws, 0, (size_t)2 * PAD_ELEMS * sizeof(float), stream);
    // initial support mask = all live (canvas0 is dense)
    hipMemsetAsync(maskP1, 0xFF, NTILES * sizeof(int), stream);

    setup_coef<<<1, 64, 0, stream>>>(theta, probs, coef);
    copy_in<<<(H * W) / 256, 256, 0, stream>>>(canvas0, bufA);

    dim3 block(256);
    dim3 grid(TILES_X, TILES_Y);

    // iter i: reads maskP[(i+1)&1], writes maskP[i&1]
    const float* cur = bufA;
    for (int i = 0; i < ITERS; ++i) {
        bool last = (i == ITERS - 1);
        float* dst = last ? out : ((i & 1) ? bufA : bufB);
        int dstPitch = last ? W : PITCH;
        int dstOff   = last ? 0 : (PITCH + 1);
        const int* mIn = ((i + 1) & 1) ? maskP1 : maskP0;
        int*       mOut = (i & 1) ? maskP1 : maskP0;
        ifs_iter<<<grid, block, 0, stream>>>(cur, dst, coef, mIn, mOut, base,
                                             dstPitch, dstOff, last ? 1 : 0);
        cur = dst;
    }
}

// Round 10
// 432.875 us; speedup vs baseline: 2.9074x; 1.0573x over previous
//
#include <hip/hip_runtime.h>

// H=W=1024, T=16, 20 iterations. Intermediates in two zero-bordered padded
// buffers: PH x PITCH floats, pixel (h,w) at [(h+1)*PITCH + (w+1)]. Zero
// borders => all 4 bilinear corners of any in-range sample are loadable
// unconditionally (zeros padding is exact).
//
// R10 = R5 (best: 416 us) + XCD-aware band swizzle:
//  - linear grid, xcd = bid & 7, slot = bid >> 3, tile = xcd*512 + slot:
//    XCD k owns tile rows 8k..8k+7 (one 128-pixel-high band). Spatially
//    adjacent tiles share source cache lines and now share an L2 -> each
//    XCD's gather footprint is ~1/8 canvas instead of all of it.
//  - hot body unchanged from R5 (quad-batched dual 8B gathers, masked).
//  - support-mask pruning (R9) reverted: canvas support never sparsifies.
constexpr int W = 1024;
constexpr int H = 1024;
constexpr int T = 16;
constexpr int ITERS = 20;
constexpr int PITCH = 1040;           // floats; 4160 B rows
constexpr int PH = H + 2;             // 1026 rows
constexpr int PAD_ELEMS = PH * PITCH;
constexpr int TILES_X = W / 16;       // 64
constexpr int TILES_Y = H / 16;       // 64
constexpr int NTILES = TILES_X * TILES_Y;

typedef float f2 __attribute__((ext_vector_type(2), aligned(4)));

// coef per transform t: {p, Ax, Bx, Cxp, Ay, By, Cyp, 0}; Cxp/Cyp include the
// +1 pad shift, so ixp = Ax*w + Bx*h + Cxp is the PADDED x coordinate.
__global__ void setup_coef(const float* __restrict__ theta,
                           const float* __restrict__ probs,
                           float* __restrict__ coef) {
    int t = threadIdx.x;
    if (t >= T) return;
    float sum = 0.f;
    for (int i = 0; i < T; ++i) sum += probs[i];
    float p = probs[t] / sum;
    const float* th = theta + 6 * t;
    float a = th[0], b = th[1], c = th[2];
    float d = th[3], e = th[4], f = th[5];
    float Cx = a * ((1.0f - (float)W) * 0.5f)
             + b * ((1.0f - (float)H) * 0.5f)
             + (c + 1.0f) * ((float)W * 0.5f) - 0.5f;
    float Cy = d * ((1.0f - (float)W) * 0.5f)
             + e * ((1.0f - (float)H) * 0.5f)
             + (f + 1.0f) * ((float)H * 0.5f) - 0.5f;
    float* o = coef + 8 * t;
    o[0] = p;  o[1] = a;  o[2] = b;  o[3] = Cx + 1.0f;
    o[4] = d;  o[5] = e;  o[6] = Cy + 1.0f; o[7] = 0.f;
}

// One thread per 16x16 tile: bit t set iff transform t's sample bbox over the
// tile intersects the valid region (conservative => exact skip).
__global__ __launch_bounds__(256) void setup_mask(const float* __restrict__ coef,
                                                  unsigned* __restrict__ mask) {
    int tile = blockIdx.x * 256 + threadIdx.x;
    if (tile >= NTILES) return;
    int tx = tile & (TILES_X - 1), ty = tile / TILES_X;
    float w0 = (float)(tx * 16), w1 = w0 + 15.f;
    float h0 = (float)(ty * 16), h1 = h0 + 15.f;
    unsigned m = 0;
    for (int t = 0; t < T; ++t) {
        float Ax = coef[t * 8 + 1], Bx = coef[t * 8 + 2], Cx = coef[t * 8 + 3];
        float Ay = coef[t * 8 + 4], By = coef[t * 8 + 5], Cy = coef[t * 8 + 6];
        float ixmin = Cx + (Ax >= 0.f ? Ax * w0 : Ax * w1) + (Bx >= 0.f ? Bx * h0 : Bx * h1);
        float ixmax = Cx + (Ax >= 0.f ? Ax * w1 : Ax * w0) + (Bx >= 0.f ? Bx * h1 : Bx * h0);
        float iymin = Cy + (Ay >= 0.f ? Ay * w0 : Ay * w1) + (By >= 0.f ? By * h0 : By * h1);
        float iymax = Cy + (Ay >= 0.f ? Ay * w1 : Ay * w0) + (By >= 0.f ? By * h1 : By * h0);
        bool hit = !(ixmax <= 0.f || ixmin >= (float)(W + 1) ||
                     iymax <= 0.f || iymin >= (float)(H + 1));
        if (hit) m |= (1u << t);
    }
    mask[tile] = m;
}

__global__ __launch_bounds__(256) void copy_in(const float* __restrict__ src,
                                               float* __restrict__ dst) {
    int i = blockIdx.x * 256 + threadIdx.x;   // i in [0, H*W)
    int h = i >> 10, w = i & 1023;
    dst[(h + 1) * PITCH + (w + 1)] = src[i];
}

__global__ __launch_bounds__(256) void ifs_iter(const float* __restrict__ in,
                                                float* __restrict__ out,
                                                const float* __restrict__ coef,
                                                const unsigned* __restrict__ mask,
                                                const float* __restrict__ base,
                                                int dstPitch, int dstOff,
                                                int add_base) {
    // compacted coefs: up to 16 active + 3 zero-pad dummies
    __shared__ float sc[(T + 3) * 8];

    // XCD band swizzle: blocks bid with bid&7==k go to XCD k (round-robin
    // dispatch heuristic); give XCD k the contiguous tile band [512k,512k+512)
    int bid  = blockIdx.x;
    int tile = (bid & 7) * (NTILES / 8) + (bid >> 3);
    int tx = tile & (TILES_X - 1);
    int ty = tile >> 6;

    unsigned tmask = mask[tile];
    int nact = __popc(tmask);
    int lid = threadIdx.x;

    if (lid < T * 8) {
        int t = lid >> 3;
        if (tmask & (1u << t)) {
            int pos = __popc(tmask & ((1u << t) - 1));
            sc[pos * 8 + (lid & 7)] = coef[lid];
        }
    }
    if (lid < 24) sc[nact * 8 + lid] = 0.f;  // dummy transforms: p=0 -> no-op
    __syncthreads();

    // 8x8-per-wave mapping; 4 waves tile a 16x16 pixel block.
    int lane = lid & 63;
    int wv   = lid >> 6;
    int w = tx * 16 + ((wv & 1) << 3) + (lane & 7);
    int h = ty * 16 + ((wv >> 1) << 3) + (lane >> 3);
    float wf = (float)w, hf = (float)h;

    float acc = 0.f;

    for (int g = 0; g < nact; g += 4) {   // wave-uniform trip count
        const float* c = sc + g * 8;
        float fx[4], fy[4], pe[4];
        int id0[4];
#pragma unroll
        for (int k = 0; k < 4; ++k) {
            const float* ck = c + k * 8;
            float p = ck[0], Ax = ck[1], Bx = ck[2], Cx = ck[3];
            float Ay = ck[4], By = ck[5], Cy = ck[6];
            float x = fmaf(Ax, wf, fmaf(Bx, hf, Cx));
            float y = fmaf(Ay, wf, fmaf(By, hf, Cy));
            float xf = floorf(x), yf = floorf(y);
            bool act = (xf >= 0.f) & (xf <= (float)W) & (yf >= 0.f) & (yf <= (float)H);
            id0[k] = act ? (int)fmaf(yf, (float)PITCH, xf) : 0;  // exact (<2^24)
            pe[k]  = act ? p : 0.f;
            fx[k] = x - xf;
            fy[k] = y - yf;
        }
        // 8 independent 8B gathers in flight (corner pairs are x-adjacent)
        f2 r0[4], r1[4];
#pragma unroll
        for (int k = 0; k < 4; ++k) {
            r0[k] = *(const f2*)(in + id0[k]);
            r1[k] = *(const f2*)(in + id0[k] + PITCH);
        }
#pragma unroll
        for (int k = 0; k < 4; ++k) {
            float top = fmaf(fx[k], r0[k].y - r0[k].x, r0[k].x);
            float bot = fmaf(fx[k], r1[k].y - r1[k].x, r1[k].x);
            acc = fmaf(pe[k], fmaf(fy[k], bot - top, top), acc);
        }
    }

    if (add_base) acc += base[0];
    out[h * dstPitch + w + dstOff] = acc;
}

extern "C" void kernel_launch(void* const* d_in, const int* in_sizes, int n_in,
                              void* d_out, int out_size, void* d_ws, size_t ws_size,
                              hipStream_t stream) {
    const float* canvas0 = (const float*)d_in[0];
    const float* theta   = (const float*)d_in[1];
    const float* probs   = (const float*)d_in[2];
    const float* base    = (const float*)d_in[3];
    float* out = (float*)d_out;

    float* bufA = (float*)d_ws;
    float* bufB = bufA + PAD_ELEMS;
    float* coef = bufB + PAD_ELEMS;
    unsigned* mask = (unsigned*)(coef + T * 8);

    // zero both padded buffers (borders must be 0; also kills 0xAA poison)
    hipMemsetAsync(d_ws, 0, (size_t)2 * PAD_ELEMS * sizeof(float), stream);

    setup_coef<<<1, 64, 0, stream>>>(theta, probs, coef);
    setup_mask<<<(NTILES + 255) / 256, 256, 0, stream>>>(coef, mask);
    copy_in<<<(H * W) / 256, 256, 0, stream>>>(canvas0, bufA);

    dim3 block(256);
    dim3 grid(NTILES);

    const float* cur = bufA;
    for (int i = 0; i < ITERS; ++i) {
        bool last = (i == ITERS - 1);
        float* dst = last ? out : ((i & 1) ? bufA : bufB);
        int dstPitch = last ? W : PITCH;
        int dstOff   = last ? 0 : (PITCH + 1);
        ifs_iter<<<grid, block, 0, stream>>>(cur, dst, coef, mask, base,
                                             dstPitch, dstOff, last ? 1 : 0);
        cur = dst;
    }
}